// Round 1
// baseline (253.396 us; speedup 1.0000x reference)
//
#include <hip/hip_runtime.h>
#include <math.h>

#define HD 512
#define BB 4
#define TT 128
#define SS 512

__device__ __forceinline__ float fast_tanh(float x) {
    x = fminf(10.f, fmaxf(-10.f, x));
    float e = __expf(2.f * x);
    return (e - 1.f) * __builtin_amdgcn_rcpf(e + 1.f);
}

// ---------------- Kernel 1: fused projections pq = q@W_s, pe = enc@W_h ----------------
// C[m,n] = sum_k A[m,k] * W[k,n].  Rows 0..511 -> query/W_s -> pq ; rows 512..2559 -> enc/W_h -> pe.
// 64x64 tile, 256 threads, 4x4 per thread, TK=16.
__global__ __launch_bounds__(256) void proj_kernel(
    const float* __restrict__ query, const float* __restrict__ enc,
    const float* __restrict__ W_s, const float* __restrict__ W_h,
    float* __restrict__ pq, float* __restrict__ pe)
{
    const int bm = blockIdx.x;            // 0..39  (8 query tiles, 32 enc tiles)
    const int bn = blockIdx.y;            // 0..7
    const bool isQ = (bm < 8);
    const float* A = isQ ? query : enc;
    const float* W = isQ ? W_s : W_h;
    float* C = isQ ? pq : pe;
    const int m0 = (isQ ? bm : bm - 8) * 64;
    const int n0 = bn * 64;

    __shared__ float As[16][65];          // transposed A tile [k][m]
    __shared__ float Bs[16][64];

    const int tid = threadIdx.x;
    const int tx = tid & 15, ty = tid >> 4;

    const int am  = tid >> 2;             // 0..63
    const int ak  = (tid & 3) * 4;        // 0,4,8,12
    const int bk  = tid >> 4;             // 0..15
    const int bn4 = (tid & 15) * 4;       // 0..60

    float acc[4][4] = {};

    for (int k0 = 0; k0 < HD; k0 += 16) {
        float4 av = *(const float4*)(A + (size_t)(m0 + am) * HD + k0 + ak);
        float4 bv = *(const float4*)(W + (size_t)(k0 + bk) * HD + n0 + bn4);
        __syncthreads();
        As[ak + 0][am] = av.x;
        As[ak + 1][am] = av.y;
        As[ak + 2][am] = av.z;
        As[ak + 3][am] = av.w;
        *(float4*)&Bs[bk][bn4] = bv;
        __syncthreads();
        #pragma unroll
        for (int k = 0; k < 16; ++k) {
            float a0 = As[k][ty * 4 + 0];
            float a1 = As[k][ty * 4 + 1];
            float a2 = As[k][ty * 4 + 2];
            float a3 = As[k][ty * 4 + 3];
            float4 b = *(const float4*)&Bs[k][tx * 4];
            acc[0][0] += a0 * b.x; acc[0][1] += a0 * b.y; acc[0][2] += a0 * b.z; acc[0][3] += a0 * b.w;
            acc[1][0] += a1 * b.x; acc[1][1] += a1 * b.y; acc[1][2] += a1 * b.z; acc[1][3] += a1 * b.w;
            acc[2][0] += a2 * b.x; acc[2][1] += a2 * b.y; acc[2][2] += a2 * b.z; acc[2][3] += a2 * b.w;
            acc[3][0] += a3 * b.x; acc[3][1] += a3 * b.y; acc[3][2] += a3 * b.z; acc[3][3] += a3 * b.w;
        }
    }
    #pragma unroll
    for (int i = 0; i < 4; ++i) {
        float4 o = make_float4(acc[i][0], acc[i][1], acc[i][2], acc[i][3]);
        *(float4*)(C + (size_t)(m0 + ty * 4 + i) * HD + n0 + tx * 4) = o;
    }
}

// ---------------- Kernel 2: score + masked softmax + context, one block per (b,t) ----------------
__global__ __launch_bounds__(256) void attn_kernel(
    const float* __restrict__ pq,   // (B*T, H)
    const float* __restrict__ pe,   // (B*S, H)
    const float* __restrict__ enc,  // (B, S, H)
    const float* __restrict__ v,    // (H)
    const int* __restrict__ src_lengths,
    float* __restrict__ ctx)        // (B*T, H)
{
    const int bt = blockIdx.x;       // 0..511
    const int b = bt >> 7;           // / T
    const int tid = threadIdx.x;
    const int lane = tid & 63;
    const int wave = tid >> 6;       // 0..3

    __shared__ float s_pq[HD];
    __shared__ float s_v[HD];
    __shared__ float s_sc[SS];
    __shared__ float s_red[8];

    const int len = src_lengths[b];

    for (int i = tid; i < HD; i += 256) {
        s_pq[i] = pq[(size_t)bt * HD + i];
        s_v[i]  = v[i];
    }
    for (int i = tid; i < SS; i += 256) s_sc[i] = -INFINITY;
    __syncthreads();

    // ---- scores: s_sc[s] = sum_h v[h] * tanh(pq[h] + pe[b,s,h]) for s < len ----
    const float* peb = pe + (size_t)b * SS * HD;
    for (int s = wave; s < len; s += 4) {
        const float* row = peb + (size_t)s * HD;
        float partial = 0.f;
        #pragma unroll
        for (int j = 0; j < 2; ++j) {
            int h = lane * 4 + j * 256;
            float4 p  = *(const float4*)(row + h);
            float4 q  = *(const float4*)(&s_pq[h]);
            float4 vv = *(const float4*)(&s_v[h]);
            partial += vv.x * fast_tanh(q.x + p.x);
            partial += vv.y * fast_tanh(q.y + p.y);
            partial += vv.z * fast_tanh(q.z + p.z);
            partial += vv.w * fast_tanh(q.w + p.w);
        }
        #pragma unroll
        for (int off = 32; off; off >>= 1)
            partial += __shfl_down(partial, off, 64);
        if (lane == 0) s_sc[s] = partial;
    }
    __syncthreads();

    // ---- masked softmax over s_sc[0..S) (entries >= len are -inf) ----
    float m = -INFINITY;
    for (int i = tid; i < SS; i += 256) m = fmaxf(m, s_sc[i]);
    #pragma unroll
    for (int off = 32; off; off >>= 1) m = fmaxf(m, __shfl_down(m, off, 64));
    if (lane == 0) s_red[wave] = m;
    __syncthreads();
    m = fmaxf(fmaxf(s_red[0], s_red[1]), fmaxf(s_red[2], s_red[3]));

    float sum = 0.f;
    for (int i = tid; i < SS; i += 256) {
        float sc = s_sc[i];
        float e = (sc > -1e30f) ? __expf(sc - m) : 0.f;
        s_sc[i] = e;
        sum += e;
    }
    #pragma unroll
    for (int off = 32; off; off >>= 1) sum += __shfl_down(sum, off, 64);
    if (lane == 0) s_red[4 + wave] = sum;
    __syncthreads();
    const float total = (s_red[4] + s_red[5]) + (s_red[6] + s_red[7]);
    const float inv = __builtin_amdgcn_rcpf(total);

    // ---- context: ctx[bt,h] = inv * sum_s e[s] * enc[b,s,h] ----
    const float* encb = enc + (size_t)b * SS * HD;
    const int h0 = tid, h1 = tid + 256;
    float c0 = 0.f, c1 = 0.f;
    #pragma unroll 4
    for (int s = 0; s < len; ++s) {
        float a = s_sc[s];
        c0 += a * encb[(size_t)s * HD + h0];
        c1 += a * encb[(size_t)s * HD + h1];
    }
    ctx[(size_t)bt * HD + h0] = c0 * inv;
    ctx[(size_t)bt * HD + h1] = c1 * inv;
}

// ---------------- Kernel 3: out = tanh([ctx | query] @ W_out) ----------------
// M=512, K=1024, N=512. 32x32 tile, 256 threads, 2x2 per thread, TK=32.
__global__ __launch_bounds__(256) void out_kernel(
    const float* __restrict__ ctx, const float* __restrict__ query,
    const float* __restrict__ W_out, float* __restrict__ out)
{
    const int m0 = blockIdx.x * 32;
    const int n0 = blockIdx.y * 32;

    __shared__ float As[32][33];   // transposed A tile [k][m]
    __shared__ float Bs[32][32];

    const int tid = threadIdx.x;
    const int tx = tid & 15, ty = tid >> 4;

    const int am  = tid >> 3;          // 0..31
    const int ak  = (tid & 7) * 4;     // 0..28
    const int bk  = tid >> 3;          // 0..31
    const int bn4 = (tid & 7) * 4;     // 0..28

    float acc[2][2] = {};

    for (int k0 = 0; k0 < 2 * HD; k0 += 32) {
        const float* A = (k0 < HD) ? ctx : query;
        const int kk = k0 & (HD - 1);
        float4 av = *(const float4*)(A + (size_t)(m0 + am) * HD + kk + ak);
        float4 bv = *(const float4*)(W_out + (size_t)(k0 + bk) * HD + n0 + bn4);
        __syncthreads();
        As[ak + 0][am] = av.x;
        As[ak + 1][am] = av.y;
        As[ak + 2][am] = av.z;
        As[ak + 3][am] = av.w;
        *(float4*)&Bs[bk][bn4] = bv;
        __syncthreads();
        #pragma unroll
        for (int k = 0; k < 32; ++k) {
            float a0 = As[k][ty * 2 + 0];
            float a1 = As[k][ty * 2 + 1];
            float b0 = Bs[k][tx * 2 + 0];
            float b1 = Bs[k][tx * 2 + 1];
            acc[0][0] += a0 * b0; acc[0][1] += a0 * b1;
            acc[1][0] += a1 * b0; acc[1][1] += a1 * b1;
        }
    }
    #pragma unroll
    for (int i = 0; i < 2; ++i) {
        #pragma unroll
        for (int j = 0; j < 2; ++j) {
            out[(size_t)(m0 + ty * 2 + i) * HD + n0 + tx * 2 + j] = fast_tanh(acc[i][j]);
        }
    }
}

extern "C" void kernel_launch(void* const* d_in, const int* in_sizes, int n_in,
                              void* d_out, int out_size, void* d_ws, size_t ws_size,
                              hipStream_t stream) {
    (void)in_sizes; (void)n_in; (void)out_size; (void)ws_size;
    const float* query = (const float*)d_in[0];   // (B,T,H)
    const float* enc   = (const float*)d_in[1];   // (B,S,H)
    const int*   lens  = (const int*)d_in[2];     // (B,)
    const float* W_h   = (const float*)d_in[3];   // (H,H)
    const float* W_s   = (const float*)d_in[4];   // (H,H)
    const float* v     = (const float*)d_in[5];   // (H,)
    const float* W_out = (const float*)d_in[6];   // (2H,H)
    float* out = (float*)d_out;

    float* ws  = (float*)d_ws;
    float* pq  = ws;                         // B*T*H  = 262144 floats
    float* pe  = pq + (size_t)BB * TT * HD;  // B*S*H  = 1048576 floats
    float* ctx = pe + (size_t)BB * SS * HD;  // B*T*H  = 262144 floats

    proj_kernel<<<dim3(40, 8), 256, 0, stream>>>(query, enc, W_s, W_h, pq, pe);
    attn_kernel<<<dim3(BB * TT), 256, 0, stream>>>(pq, pe, enc, v, lens, ctx);
    out_kernel<<<dim3(16, 16), 256, 0, stream>>>(ctx, query, W_out, out);
}

// Round 2
// 186.003 us; speedup vs baseline: 1.3623x; 1.3623x over previous
//
#include <hip/hip_runtime.h>
#include <math.h>

#define HD 512
#define BB 4
#define TT 128
#define SS 512

// tanh(x) = 1 - 2/(e^{2x}+1). No clamp needed: exp->inf => 1, exp->0 => -1.
__device__ __forceinline__ float tanh_e(float x) {
    float t = __builtin_amdgcn_rcpf(__expf(2.f * x) + 1.f);
    return fmaf(-2.f, t, 1.f);
}

// ---------------- Kernel 1: pq = q@W_s (row-major), peT = (enc@W_h)^T per batch (B,H,S) --------
// 32x64 (MxN) tiles, 256 threads, 2x4 per thread, TK=16, register prefetch.
__global__ __launch_bounds__(256) void proj_kernel(
    const float* __restrict__ query, const float* __restrict__ enc,
    const float* __restrict__ W_s, const float* __restrict__ W_h,
    float* __restrict__ pq, float* __restrict__ peT)
{
    const int bm = blockIdx.x;            // 0..79 (16 query tiles, 64 enc tiles)
    const int bn = blockIdx.y;            // 0..7
    const bool isQ = (bm < 16);
    const float* A = isQ ? query : enc;
    const float* W = isQ ? W_s : W_h;
    const int m0 = (isQ ? bm : bm - 16) * 32;
    const int n0 = bn * 64;

    __shared__ float As[16][34];          // transposed A tile [k][m], row=136B (8B aligned)
    __shared__ float Bs[16][64];

    const int tid = threadIdx.x;
    const int tx = tid & 15, ty = tid >> 4;   // tx: n (x4), ty: m (x2)

    const int am = tid >> 3;              // 0..31
    const int ak = (tid & 7) * 2;         // 0..14
    const int bk = tid >> 4;              // 0..15
    const int bn4 = (tid & 15) * 4;       // 0..60

    float acc[2][4] = {};

    float2 av = *(const float2*)(A + (size_t)(m0 + am) * HD + ak);
    float4 bv = *(const float4*)(W + (size_t)bk * HD + n0 + bn4);

    for (int k0 = 0; k0 < HD; k0 += 16) {
        __syncthreads();
        As[ak + 0][am] = av.x;
        As[ak + 1][am] = av.y;
        *(float4*)&Bs[bk][bn4] = bv;
        __syncthreads();
        if (k0 + 16 < HD) {
            av = *(const float2*)(A + (size_t)(m0 + am) * HD + k0 + 16 + ak);
            bv = *(const float4*)(W + (size_t)(k0 + 16 + bk) * HD + n0 + bn4);
        }
        #pragma unroll
        for (int k = 0; k < 16; ++k) {
            float2 a2 = *(const float2*)&As[k][ty * 2];
            float4 b4 = *(const float4*)&Bs[k][tx * 4];
            acc[0][0] += a2.x * b4.x; acc[0][1] += a2.x * b4.y;
            acc[0][2] += a2.x * b4.z; acc[0][3] += a2.x * b4.w;
            acc[1][0] += a2.y * b4.x; acc[1][1] += a2.y * b4.y;
            acc[1][2] += a2.y * b4.z; acc[1][3] += a2.y * b4.w;
        }
    }

    if (isQ) {
        #pragma unroll
        for (int i = 0; i < 2; ++i) {
            float4 o = make_float4(acc[i][0], acc[i][1], acc[i][2], acc[i][3]);
            *(float4*)(pq + (size_t)(m0 + ty * 2 + i) * HD + n0 + tx * 4) = o;
        }
    } else {
        #pragma unroll
        for (int i = 0; i < 2; ++i) {
            const int m = m0 + ty * 2 + i;        // enc-local row 0..2047
            const int b = m >> 9, s = m & 511;
            #pragma unroll
            for (int j = 0; j < 4; ++j)
                peT[(size_t)b * HD * SS + (size_t)(n0 + tx * 4 + j) * SS + s] = acc[i][j];
        }
    }
}

// ---------------- Kernel 2: scores + masked softmax, one block of 512 per (b,t) ----------------
// Thread tid == s. Reads peT columns coalesced; no per-score reduction needed.
__global__ __launch_bounds__(512) void score_kernel(
    const float* __restrict__ pq,   // (B*T, H)
    const float* __restrict__ peT,  // (B, H, S)
    const float* __restrict__ v,    // (H)
    const int* __restrict__ lens,
    float* __restrict__ alpha)      // (B*T, S), normalized, 0 for s>=len
{
    const int bt = blockIdx.x;
    const int b = bt >> 7;
    const int tid = threadIdx.x;    // == s
    const int wave = tid >> 6;

    __shared__ float s_pq[HD];
    __shared__ float s_v[HD];
    __shared__ float s_red[16];

    const int len = lens[b];
    s_pq[tid] = pq[(size_t)bt * HD + tid];
    s_v[tid]  = v[tid];
    __syncthreads();

    float sc = -INFINITY;
    if (tid < len) {
        const float* col = peT + (size_t)b * HD * SS + tid;
        float acc = 0.f;
        for (int h = 0; h < HD; h += 8) {
            float p[8];
            #pragma unroll
            for (int j = 0; j < 8; ++j) p[j] = col[(size_t)(h + j) * SS];
            float4 q0 = *(const float4*)&s_pq[h];
            float4 q1 = *(const float4*)&s_pq[h + 4];
            float4 w0 = *(const float4*)&s_v[h];
            float4 w1 = *(const float4*)&s_v[h + 4];
            acc = fmaf(w0.x, tanh_e(q0.x + p[0]), acc);
            acc = fmaf(w0.y, tanh_e(q0.y + p[1]), acc);
            acc = fmaf(w0.z, tanh_e(q0.z + p[2]), acc);
            acc = fmaf(w0.w, tanh_e(q0.w + p[3]), acc);
            acc = fmaf(w1.x, tanh_e(q1.x + p[4]), acc);
            acc = fmaf(w1.y, tanh_e(q1.y + p[5]), acc);
            acc = fmaf(w1.z, tanh_e(q1.z + p[6]), acc);
            acc = fmaf(w1.w, tanh_e(q1.w + p[7]), acc);
        }
        sc = acc;
    }

    // block softmax over 512 threads
    float m = sc;
    #pragma unroll
    for (int off = 32; off; off >>= 1) m = fmaxf(m, __shfl_xor(m, off, 64));
    if ((tid & 63) == 0) s_red[wave] = m;
    __syncthreads();
    m = s_red[0];
    #pragma unroll
    for (int w = 1; w < 8; ++w) m = fmaxf(m, s_red[w]);

    float e = (tid < len) ? __expf(sc - m) : 0.f;
    float sum = e;
    #pragma unroll
    for (int off = 32; off; off >>= 1) sum += __shfl_xor(sum, off, 64);
    if ((tid & 63) == 0) s_red[8 + wave] = sum;
    __syncthreads();
    float total = s_red[8];
    #pragma unroll
    for (int w = 1; w < 8; ++w) total += s_red[8 + w];

    alpha[(size_t)bt * SS + tid] = e * __builtin_amdgcn_rcpf(total);
}

// ---------------- Kernel 3: ctx = alpha @ enc, tiled (16t x 64h per block) ----------------
__global__ __launch_bounds__(256) void ctx_kernel(
    const float* __restrict__ alpha, const float* __restrict__ enc,
    const int* __restrict__ lens, float* __restrict__ ctx)
{
    const int b = blockIdx.x;
    const int t0 = blockIdx.y * 16;
    const int h0 = blockIdx.z * 64;

    __shared__ float sA[16][64];   // alpha tile [t][s]
    __shared__ float sE[64][64];   // enc tile [s][h]

    const int tid = threadIdx.x;
    const int tx = tid & 63;       // h
    const int ty = tid >> 6;       // 0..3
    const int len = lens[b];

    float acc[4] = {0.f, 0.f, 0.f, 0.f};

    for (int s0 = 0; s0 < len; s0 += 64) {
        __syncthreads();
        #pragma unroll
        for (int it = 0; it < 4; ++it) {
            int idx = tid + it * 256;                   // 0..1023
            sA[idx >> 6][idx & 63] =
                alpha[(size_t)(b * TT + t0 + (idx >> 6)) * SS + s0 + (idx & 63)];
        }
        #pragma unroll
        for (int it = 0; it < 4; ++it) {
            int f = tid + it * 256;                     // float4 idx 0..1023
            int r = f >> 4, c4 = (f & 15) * 4;
            *(float4*)&sE[r][c4] =
                *(const float4*)(enc + ((size_t)(b * SS + s0 + r) * HD) + h0 + c4);
        }
        __syncthreads();
        #pragma unroll 8
        for (int s = 0; s < 64; ++s) {
            float e = sE[s][tx];
            acc[0] = fmaf(sA[0 + ty * 4 + 0][s], e, acc[0]);
            acc[1] = fmaf(sA[0 + ty * 4 + 1][s], e, acc[1]);
            acc[2] = fmaf(sA[0 + ty * 4 + 2][s], e, acc[2]);
            acc[3] = fmaf(sA[0 + ty * 4 + 3][s], e, acc[3]);
        }
    }
    #pragma unroll
    for (int i = 0; i < 4; ++i)
        ctx[(size_t)(b * TT + t0 + ty * 4 + i) * HD + h0 + tx] = acc[i];
}

// ---------------- Kernel 4: split-K partial GEMM for out = [ctx|q] @ W_out ----------------
// M=512,N=512,K=1024 split into 4 chunks of 256. 32x32 tile, 2x2/thread, TK=32, prefetch.
__global__ __launch_bounds__(256) void out_gemm_kernel(
    const float* __restrict__ ctx, const float* __restrict__ query,
    const float* __restrict__ W_out, float* __restrict__ pp)
{
    const int m0 = blockIdx.x * 32;
    const int n0 = blockIdx.y * 32;
    const int kc = blockIdx.z;                 // 0..3
    const float* A = (kc < 2) ? ctx : query;
    const int kk = (kc & 1) * 256;             // column offset within A

    __shared__ float As[32][34];               // [k][m], row 136B
    __shared__ float Bs[32][32];

    const int tid = threadIdx.x;
    const int tx = tid & 15, ty = tid >> 4;

    const int am = tid >> 3;                   // 0..31
    const int ak = (tid & 7) * 4;              // 0..28
    const int bk = tid >> 3;                   // 0..31
    const int bn = (tid & 7) * 4;              // 0..28

    float acc[2][2] = {};

    float4 av = *(const float4*)(A + (size_t)(m0 + am) * HD + kk + ak);
    float4 bv = *(const float4*)(W_out + (size_t)(kc * 256 + bk) * HD + n0 + bn);

    for (int kt = 0; kt < 256; kt += 32) {
        __syncthreads();
        As[ak + 0][am] = av.x;
        As[ak + 1][am] = av.y;
        As[ak + 2][am] = av.z;
        As[ak + 3][am] = av.w;
        *(float4*)&Bs[bk][bn] = bv;
        __syncthreads();
        if (kt + 32 < 256) {
            av = *(const float4*)(A + (size_t)(m0 + am) * HD + kk + kt + 32 + ak);
            bv = *(const float4*)(W_out + (size_t)(kc * 256 + kt + 32 + bk) * HD + n0 + bn);
        }
        #pragma unroll
        for (int k = 0; k < 32; ++k) {
            float2 a2 = *(const float2*)&As[k][ty * 2];
            float2 b2 = *(const float2*)&Bs[k][tx * 2];
            acc[0][0] += a2.x * b2.x; acc[0][1] += a2.x * b2.y;
            acc[1][0] += a2.y * b2.x; acc[1][1] += a2.y * b2.y;
        }
    }
    #pragma unroll
    for (int i = 0; i < 2; ++i)
        #pragma unroll
        for (int j = 0; j < 2; ++j)
            pp[(size_t)kc * (HD * HD) + (size_t)(m0 + ty * 2 + i) * HD + n0 + tx * 2 + j]
                = acc[i][j];
}

// ---------------- Kernel 5: out = tanh(sum of 4 partials) ----------------
__global__ __launch_bounds__(256) void out_epi_kernel(
    const float* __restrict__ pp, float* __restrict__ out)
{
    const int i = blockIdx.x * 256 + threadIdx.x;      // float4 index, 65536 total
    const float4* p4 = (const float4*)pp;
    float4 a = p4[i];
    float4 b = p4[i + 65536];
    float4 c = p4[i + 2 * 65536];
    float4 d = p4[i + 3 * 65536];
    float4 o;
    o.x = tanh_e(a.x + b.x + c.x + d.x);
    o.y = tanh_e(a.y + b.y + c.y + d.y);
    o.z = tanh_e(a.z + b.z + c.z + d.z);
    o.w = tanh_e(a.w + b.w + c.w + d.w);
    ((float4*)out)[i] = o;
}

extern "C" void kernel_launch(void* const* d_in, const int* in_sizes, int n_in,
                              void* d_out, int out_size, void* d_ws, size_t ws_size,
                              hipStream_t stream) {
    (void)in_sizes; (void)n_in; (void)out_size; (void)ws_size;
    const float* query = (const float*)d_in[0];   // (B,T,H)
    const float* enc   = (const float*)d_in[1];   // (B,S,H)
    const int*   lens  = (const int*)d_in[2];     // (B,)
    const float* W_h   = (const float*)d_in[3];   // (H,H)
    const float* W_s   = (const float*)d_in[4];   // (H,H)
    const float* v     = (const float*)d_in[5];   // (H,)
    const float* W_out = (const float*)d_in[6];   // (2H,H)
    float* out = (float*)d_out;

    float* ws    = (float*)d_ws;
    float* pq    = ws;                              // B*T*H   = 262144 floats (1 MB)
    float* peT   = pq + (size_t)BB * TT * HD;       // B*H*S   = 1048576 floats (4 MB)
    float* alpha = peT + (size_t)BB * HD * SS;      // B*T*S   = 262144 floats (1 MB)
    float* ctx   = alpha + (size_t)BB * TT * SS;    // B*T*H   = 262144 floats (1 MB)
    float* pp    = peT;                             // alias: 4*H*H = 4 MB, peT dead by then

    proj_kernel<<<dim3(80, 8), 256, 0, stream>>>(query, enc, W_s, W_h, pq, peT);
    score_kernel<<<dim3(BB * TT), 512, 0, stream>>>(pq, peT, v, lens, alpha);
    ctx_kernel<<<dim3(BB, TT / 16, HD / 64), 256, 0, stream>>>(alpha, enc, lens, ctx);
    out_gemm_kernel<<<dim3(16, 16, 4), 256, 0, stream>>>(ctx, query, W_out, pp);
    out_epi_kernel<<<dim3(256), 256, 0, stream>>>(pp, out);
}

// Round 3
// 158.482 us; speedup vs baseline: 1.5989x; 1.1737x over previous
//
#include <hip/hip_runtime.h>
#include <math.h>

#define HD 512
#define BB 4
#define TT 128
#define SS 512

typedef __attribute__((ext_vector_type(8))) short short8;
typedef __attribute__((ext_vector_type(4))) float floatx4;
typedef unsigned short ushort_t;

__device__ __forceinline__ float tanh_e(float x) {
    float t = __builtin_amdgcn_rcpf(__expf(2.f * x) + 1.f);
    return fmaf(-2.f, t, 1.f);
}
__device__ __forceinline__ ushort_t f2bf(float x) {      // RNE fp32->bf16
    unsigned int u = __float_as_uint(x);
    u += 0x7fffu + ((u >> 16) & 1u);
    return (ushort_t)(u >> 16);
}
__device__ __forceinline__ float bf2f(ushort_t h) {
    return __uint_as_float(((unsigned int)h) << 16);
}

// ---------------- Kernel 0: transpose + cast weights to bf16 [n][k] ----------------
__global__ __launch_bounds__(256) void wtrans_kernel(
    const float* __restrict__ Ws, const float* __restrict__ Wh,
    const float* __restrict__ Wo,
    ushort_t* __restrict__ Ts, ushort_t* __restrict__ Th, ushort_t* __restrict__ To)
{
    const int bid = blockIdx.x;
    const float* src; ushort_t* dst; int K, N, l;
    if (bid < 256)      { src = Ws; dst = Ts; K = 512;  N = 512; l = bid; }
    else if (bid < 512) { src = Wh; dst = Th; K = 512;  N = 512; l = bid - 256; }
    else                { src = Wo; dst = To; K = 1024; N = 512; l = bid - 512; }
    const int tk = l % (K / 32), tn = l / (K / 32);
    const int k0 = tk * 32, n0 = tn * 32;

    __shared__ ushort_t tile[32][36];
    const int r  = threadIdx.x >> 3;
    const int c4 = (threadIdx.x & 7) * 4;

    float4 s = *(const float4*)(src + (size_t)(k0 + r) * N + n0 + c4);
    tile[r][c4 + 0] = f2bf(s.x);
    tile[r][c4 + 1] = f2bf(s.y);
    tile[r][c4 + 2] = f2bf(s.z);
    tile[r][c4 + 3] = f2bf(s.w);
    __syncthreads();
    ushort4 o;
    o.x = tile[c4 + 0][r];
    o.y = tile[c4 + 1][r];
    o.z = tile[c4 + 2][r];
    o.w = tile[c4 + 3][r];
    *(ushort4*)&dst[(size_t)(n0 + r) * K + k0 + c4] = o;
}

// ---------------- Kernel 1: MFMA proj: pq = q@W_s (f32), peT = bf16((enc@W_h)^T) ----------------
// 64x64 C-tiles, 256 thr (4 waves, each 32x32 = 2x2 MFMA 16x16x32), K-chunks of 32.
#define LDP 40   // padded bf16 row stride for [row][k(32)] tiles
__global__ __launch_bounds__(256) void proj_kernel(
    const float* __restrict__ query, const float* __restrict__ enc,
    const ushort_t* __restrict__ WTs, const ushort_t* __restrict__ WTh,
    float* __restrict__ pq, ushort_t* __restrict__ peT)
{
    const int bm = blockIdx.x;            // 0..39: 8 query tiles, 32 enc tiles
    const int bn = blockIdx.y;            // 0..7
    const bool isQ = (bm < 8);
    const float* A = isQ ? query : enc;
    const ushort_t* WT = isQ ? WTs : WTh;
    const int m0 = (isQ ? bm : bm - 8) * 64;
    const int n0 = bn * 64;

    __shared__ ushort_t As[64 * LDP];     // [m][k]
    __shared__ ushort_t Bs[64 * LDP];     // [n][k]

    const int tid = threadIdx.x;
    const int lane = tid & 63, w = tid >> 6;
    const int quad = lane >> 4, lrow = lane & 15;
    const int mw = (w & 1) * 32, nw = (w >> 1) * 32;

    const int ar = tid >> 2;              // 0..63
    const int ac = (tid & 3) * 8;         // 0,8,16,24

    floatx4 zero = {0.f, 0.f, 0.f, 0.f};
    floatx4 acc[2][2] = {{zero, zero}, {zero, zero}};

    float4 a0 = *(const float4*)(A + (size_t)(m0 + ar) * HD + ac);
    float4 a1 = *(const float4*)(A + (size_t)(m0 + ar) * HD + ac + 4);
    uint4  bld = *(const uint4*)&WT[(size_t)(n0 + ar) * HD + ac];

    for (int k0 = 0; k0 < HD; k0 += 32) {
        __syncthreads();
        uint4 ap;
        ap.x = (unsigned)f2bf(a0.x) | ((unsigned)f2bf(a0.y) << 16);
        ap.y = (unsigned)f2bf(a0.z) | ((unsigned)f2bf(a0.w) << 16);
        ap.z = (unsigned)f2bf(a1.x) | ((unsigned)f2bf(a1.y) << 16);
        ap.w = (unsigned)f2bf(a1.z) | ((unsigned)f2bf(a1.w) << 16);
        *(uint4*)&As[ar * LDP + ac] = ap;
        *(uint4*)&Bs[ar * LDP + ac] = bld;
        __syncthreads();
        if (k0 + 32 < HD) {
            a0  = *(const float4*)(A + (size_t)(m0 + ar) * HD + k0 + 32 + ac);
            a1  = *(const float4*)(A + (size_t)(m0 + ar) * HD + k0 + 32 + ac + 4);
            bld = *(const uint4*)&WT[(size_t)(n0 + ar) * HD + k0 + 32 + ac];
        }
        short8 af[2], bf[2];
        #pragma unroll
        for (int i = 0; i < 2; ++i)
            af[i] = *(const short8*)&As[(mw + i * 16 + lrow) * LDP + quad * 8];
        #pragma unroll
        for (int j = 0; j < 2; ++j)
            bf[j] = *(const short8*)&Bs[(nw + j * 16 + lrow) * LDP + quad * 8];
        #pragma unroll
        for (int i = 0; i < 2; ++i)
            #pragma unroll
            for (int j = 0; j < 2; ++j)
                acc[i][j] = __builtin_amdgcn_mfma_f32_16x16x32_bf16(af[i], bf[j], acc[i][j], 0, 0, 0);
    }

    if (isQ) {
        #pragma unroll
        for (int i = 0; i < 2; ++i)
            #pragma unroll
            for (int j = 0; j < 2; ++j)
                #pragma unroll
                for (int r = 0; r < 4; ++r) {
                    const int row = m0 + mw + i * 16 + quad * 4 + r;
                    const int col = n0 + nw + j * 16 + lrow;
                    pq[(size_t)row * HD + col] = acc[i][j][r];
                }
    } else {
        #pragma unroll
        for (int i = 0; i < 2; ++i)
            #pragma unroll
            for (int j = 0; j < 2; ++j) {
                const int gm = m0 + mw + i * 16 + quad * 4;   // enc-local row (4 consecutive)
                const int b = gm >> 9, s = gm & 511;
                const int col = n0 + nw + j * 16 + lrow;
                ushort4 o;
                o.x = f2bf(acc[i][j][0]);
                o.y = f2bf(acc[i][j][1]);
                o.z = f2bf(acc[i][j][2]);
                o.w = f2bf(acc[i][j][3]);
                *(ushort4*)&peT[((size_t)b * HD + col) * SS + s] = o;
            }
    }
}

// ---------------- Kernel 2: partial scores, grid (B*T, 4), thread==s ----------------
__global__ __launch_bounds__(512) void score_part_kernel(
    const float* __restrict__ pq, const ushort_t* __restrict__ peT,
    const float* __restrict__ v, const int* __restrict__ lens,
    _Float16* __restrict__ sp)
{
    const int bt = blockIdx.x;
    const int hq = blockIdx.y;
    const int b = bt >> 7;
    const int tid = threadIdx.x;          // == s
    const int h0 = hq * 128;

    __shared__ float s_a[128];            // 2*pq
    __shared__ float s_w[128];            // v
    if (tid < 128) {
        s_a[tid] = 2.f * pq[(size_t)bt * HD + h0 + tid];
        s_w[tid] = v[h0 + tid];
    }
    __syncthreads();
    const int len = lens[b];
    if (tid >= len) return;

    const ushort_t* col = peT + ((size_t)b * HD + h0) * SS + tid;
    float acc = 0.f;
    for (int hh = 0; hh < 128; hh += 8) {
        #pragma unroll
        for (int j = 0; j < 8; ++j) {
            float p = bf2f(col[(size_t)(hh + j) * SS]);
            float t = __builtin_amdgcn_rcpf(__expf(fmaf(2.f, p, s_a[hh + j])) + 1.f);
            acc = fmaf(s_w[hh + j], fmaf(-2.f, t, 1.f), acc);
        }
    }
    sp[((size_t)hq * (BB * TT) + bt) * SS + tid] = (_Float16)acc;
}

// ---------------- Kernel 3: combine partials + masked softmax -> alpha ----------------
__global__ __launch_bounds__(512) void combine_kernel(
    const _Float16* __restrict__ sp, const int* __restrict__ lens,
    float* __restrict__ alpha)
{
    const int bt = blockIdx.x;
    const int b = bt >> 7;
    const int tid = threadIdx.x;
    const int wave = tid >> 6;
    __shared__ float s_red[16];

    const int len = lens[b];
    float sc = -INFINITY;
    if (tid < len) {
        const size_t i = (size_t)bt * SS + tid;
        const size_t st = (size_t)BB * TT * SS;
        sc = (float)sp[i] + (float)sp[i + st] + (float)sp[i + 2 * st] + (float)sp[i + 3 * st];
    }
    float m = sc;
    #pragma unroll
    for (int off = 32; off; off >>= 1) m = fmaxf(m, __shfl_xor(m, off, 64));
    if ((tid & 63) == 0) s_red[wave] = m;
    __syncthreads();
    m = s_red[0];
    #pragma unroll
    for (int w2 = 1; w2 < 8; ++w2) m = fmaxf(m, s_red[w2]);

    float e = (tid < len) ? __expf(sc - m) : 0.f;
    float sum = e;
    #pragma unroll
    for (int off = 32; off; off >>= 1) sum += __shfl_xor(sum, off, 64);
    if ((tid & 63) == 0) s_red[8 + wave] = sum;
    __syncthreads();
    float total = s_red[8];
    #pragma unroll
    for (int w2 = 1; w2 < 8; ++w2) total += s_red[8 + w2];

    alpha[(size_t)bt * SS + tid] = e * __builtin_amdgcn_rcpf(total);
}

// ---------------- Kernel 4: ctx = alpha @ enc, tiled (16t x 64h per block) ----------------
__global__ __launch_bounds__(256) void ctx_kernel(
    const float* __restrict__ alpha, const float* __restrict__ enc,
    const int* __restrict__ lens, float* __restrict__ ctx)
{
    const int b = blockIdx.x;
    const int t0 = blockIdx.y * 16;
    const int h0 = blockIdx.z * 64;

    __shared__ float sA[16][64];
    __shared__ float sE[64][64];

    const int tid = threadIdx.x;
    const int tx = tid & 63;
    const int ty = tid >> 6;
    const int len = lens[b];

    float acc[4] = {0.f, 0.f, 0.f, 0.f};

    for (int s0 = 0; s0 < len; s0 += 64) {
        __syncthreads();
        #pragma unroll
        for (int it = 0; it < 4; ++it) {
            int idx = tid + it * 256;
            sA[idx >> 6][idx & 63] =
                alpha[(size_t)(b * TT + t0 + (idx >> 6)) * SS + s0 + (idx & 63)];
        }
        #pragma unroll
        for (int it = 0; it < 4; ++it) {
            int f = tid + it * 256;
            int r = f >> 4, c4 = (f & 15) * 4;
            *(float4*)&sE[r][c4] =
                *(const float4*)(enc + ((size_t)(b * SS + s0 + r) * HD) + h0 + c4);
        }
        __syncthreads();
        #pragma unroll 8
        for (int s = 0; s < 64; ++s) {
            float e = sE[s][tx];
            acc[0] = fmaf(sA[ty * 4 + 0][s], e, acc[0]);
            acc[1] = fmaf(sA[ty * 4 + 1][s], e, acc[1]);
            acc[2] = fmaf(sA[ty * 4 + 2][s], e, acc[2]);
            acc[3] = fmaf(sA[ty * 4 + 3][s], e, acc[3]);
        }
    }
    #pragma unroll
    for (int i = 0; i < 4; ++i)
        ctx[(size_t)(b * TT + t0 + ty * 4 + i) * HD + h0 + tx] = acc[i];
}

// ---------------- Kernel 5: out = tanh([ctx|q] @ W_out), MFMA, 32x64 tiles ----------------
__global__ __launch_bounds__(256) void out_kernel(
    const float* __restrict__ ctx, const float* __restrict__ query,
    const ushort_t* __restrict__ WTo, float* __restrict__ out)
{
    const int m0 = blockIdx.x * 32;
    const int n0 = blockIdx.y * 64;

    __shared__ ushort_t As[32 * LDP];     // [m][k]
    __shared__ ushort_t Bs[64 * LDP];     // [n][k]

    const int tid = threadIdx.x;
    const int lane = tid & 63, w = tid >> 6;
    const int quad = lane >> 4, lrow = lane & 15;
    const int mw = (w & 1) * 16, nw = (w >> 1) * 32;

    const int ar = tid >> 3;              // 0..31
    const int acA = (tid & 7) * 4;        // 0..28
    const int br = tid >> 2;              // 0..63
    const int bc = (tid & 3) * 8;         // 0,8,16,24

    floatx4 zero = {0.f, 0.f, 0.f, 0.f};
    floatx4 acc[2] = {zero, zero};

    float4 av = *(const float4*)(ctx + (size_t)(m0 + ar) * HD + acA);
    uint4  bv = *(const uint4*)&WTo[(size_t)(n0 + br) * (2 * HD) + bc];

    for (int k0 = 0; k0 < 2 * HD; k0 += 32) {
        __syncthreads();
        ushort4 ap;
        ap.x = f2bf(av.x); ap.y = f2bf(av.y); ap.z = f2bf(av.z); ap.w = f2bf(av.w);
        *(ushort4*)&As[ar * LDP + acA] = ap;
        *(uint4*)&Bs[br * LDP + bc] = bv;
        __syncthreads();
        if (k0 + 32 < 2 * HD) {
            const int kn = k0 + 32;
            const float* A = (kn < HD) ? ctx : query;
            av = *(const float4*)(A + (size_t)(m0 + ar) * HD + (kn & (HD - 1)) + acA);
            bv = *(const uint4*)&WTo[(size_t)(n0 + br) * (2 * HD) + kn + bc];
        }
        short8 af = *(const short8*)&As[(mw + lrow) * LDP + quad * 8];
        #pragma unroll
        for (int j = 0; j < 2; ++j) {
            short8 bf = *(const short8*)&Bs[(nw + j * 16 + lrow) * LDP + quad * 8];
            acc[j] = __builtin_amdgcn_mfma_f32_16x16x32_bf16(af, bf, acc[j], 0, 0, 0);
        }
    }
    #pragma unroll
    for (int j = 0; j < 2; ++j)
        #pragma unroll
        for (int r = 0; r < 4; ++r) {
            const int row = m0 + mw + quad * 4 + r;
            const int col = n0 + nw + j * 16 + lrow;
            out[(size_t)row * HD + col] = tanh_e(acc[j][r]);
        }
}

extern "C" void kernel_launch(void* const* d_in, const int* in_sizes, int n_in,
                              void* d_out, int out_size, void* d_ws, size_t ws_size,
                              hipStream_t stream) {
    (void)in_sizes; (void)n_in; (void)out_size; (void)ws_size;
    const float* query = (const float*)d_in[0];   // (B,T,H)
    const float* enc   = (const float*)d_in[1];   // (B,S,H)
    const int*   lens  = (const int*)d_in[2];     // (B,)
    const float* W_h   = (const float*)d_in[3];   // (H,H)
    const float* W_s   = (const float*)d_in[4];   // (H,H)
    const float* v     = (const float*)d_in[5];   // (H,)
    const float* W_out = (const float*)d_in[6];   // (2H,H)
    float* out = (float*)d_out;

    // workspace layout (7 MB total)
    ushort_t* WTs = (ushort_t*)d_ws;                          // 512 KB
    ushort_t* WTh = WTs + (size_t)HD * HD;                    // 512 KB
    ushort_t* WTo = WTh + (size_t)HD * HD;                    // 1 MB
    float*    pq  = (float*)(WTo + (size_t)HD * 2 * HD);      // 1 MB
    ushort_t* peT = (ushort_t*)(pq + (size_t)BB * TT * HD);   // 2 MB (bf16)
    _Float16* sp  = (_Float16*)(peT + (size_t)BB * HD * SS);  // 2 MB (fp16 partials)
    float* alpha = pq;                    // alias: pq dead after score_part
    float* ctxp  = (float*)peT;           // alias: peT dead after score_part

    wtrans_kernel<<<dim3(1024), 256, 0, stream>>>(W_s, W_h, W_out, WTs, WTh, WTo);
    proj_kernel<<<dim3(40, 8), 256, 0, stream>>>(query, enc, WTs, WTh, pq, peT);
    score_part_kernel<<<dim3(BB * TT, 4), 512, 0, stream>>>(pq, peT, v, lens, sp);
    combine_kernel<<<dim3(BB * TT), 512, 0, stream>>>(sp, lens, alpha);
    ctx_kernel<<<dim3(BB, TT / 16, HD / 64), 256, 0, stream>>>(alpha, enc, lens, ctxp);
    out_kernel<<<dim3(16, 8), 256, 0, stream>>>(ctxp, query, WTo, out);
}

// Round 4
// 152.662 us; speedup vs baseline: 1.6598x; 1.0381x over previous
//
#include <hip/hip_runtime.h>
#include <math.h>

#define HD 512
#define BB 4
#define TT 128
#define SS 512
#define CEXP 2.88539008177792681f   // 2*log2(e)

typedef __attribute__((ext_vector_type(8))) short short8;
typedef __attribute__((ext_vector_type(4))) float floatx4;
typedef unsigned short ushort_t;
typedef unsigned int uint_t;

__device__ __forceinline__ float tanh_e(float x) {
    float t = __builtin_amdgcn_rcpf(__expf(2.f * x) + 1.f);
    return fmaf(-2.f, t, 1.f);
}
__device__ __forceinline__ ushort_t f2bf(float x) {      // RNE fp32->bf16
    unsigned int u = __float_as_uint(x);
    u += 0x7fffu + ((u >> 16) & 1u);
    return (ushort_t)(u >> 16);
}

// ---------------- Kernel 0: weight transpose/cast to bf16 [n][k] + query cast into cq ----------
__global__ __launch_bounds__(256) void wtrans_kernel(
    const float* __restrict__ Ws, const float* __restrict__ Wh,
    const float* __restrict__ Wo, const float* __restrict__ query,
    ushort_t* __restrict__ Ts, ushort_t* __restrict__ Th, ushort_t* __restrict__ To,
    ushort_t* __restrict__ cq)
{
    const int bid = blockIdx.x;
    if (bid < 1024) {
        const float* src; ushort_t* dst; int K, N, l;
        if (bid < 256)      { src = Ws; dst = Ts; K = 512;  N = 512; l = bid; }
        else if (bid < 512) { src = Wh; dst = Th; K = 512;  N = 512; l = bid - 256; }
        else                { src = Wo; dst = To; K = 1024; N = 512; l = bid - 512; }
        const int tk = l % (K / 32), tn = l / (K / 32);
        const int k0 = tk * 32, n0 = tn * 32;

        __shared__ ushort_t tile[32][36];
        const int r  = threadIdx.x >> 3;
        const int c4 = (threadIdx.x & 7) * 4;

        float4 s = *(const float4*)(src + (size_t)(k0 + r) * N + n0 + c4);
        tile[r][c4 + 0] = f2bf(s.x);
        tile[r][c4 + 1] = f2bf(s.y);
        tile[r][c4 + 2] = f2bf(s.z);
        tile[r][c4 + 3] = f2bf(s.w);
        __syncthreads();
        ushort4 o;
        o.x = tile[c4 + 0][r];
        o.y = tile[c4 + 1][r];
        o.z = tile[c4 + 2][r];
        o.w = tile[c4 + 3][r];
        *(ushort4*)&dst[(size_t)(n0 + r) * K + k0 + c4] = o;
    } else {
        // query -> bf16 into cq[m][512 + h]
        const int idx = ((bid - 1024) * 256 + threadIdx.x) * 8;   // 0..262136
        const int m = idx >> 9, h = idx & 511;
        float4 q0 = *(const float4*)(query + (size_t)m * HD + h);
        float4 q1 = *(const float4*)(query + (size_t)m * HD + h + 4);
        uint4 o;
        o.x = (uint_t)f2bf(q0.x) | ((uint_t)f2bf(q0.y) << 16);
        o.y = (uint_t)f2bf(q0.z) | ((uint_t)f2bf(q0.w) << 16);
        o.z = (uint_t)f2bf(q1.x) | ((uint_t)f2bf(q1.y) << 16);
        o.w = (uint_t)f2bf(q1.z) | ((uint_t)f2bf(q1.w) << 16);
        *(uint4*)&cq[(size_t)m * 1024 + 512 + h] = o;
    }
}

// ---------------- Kernel 1: MFMA proj: pq = q@W_s (f32), peT = bf16((enc@W_h)^T) ----------------
#define LDP 40   // padded bf16 row stride for [row][k(32)] tiles
__global__ __launch_bounds__(256) void proj_kernel(
    const float* __restrict__ query, const float* __restrict__ enc,
    const ushort_t* __restrict__ WTs, const ushort_t* __restrict__ WTh,
    float* __restrict__ pq, ushort_t* __restrict__ peT)
{
    const int bm = blockIdx.x;            // 0..39: 8 query tiles, 32 enc tiles
    const int bn = blockIdx.y;            // 0..7
    const bool isQ = (bm < 8);
    const float* A = isQ ? query : enc;
    const ushort_t* WT = isQ ? WTs : WTh;
    const int m0 = (isQ ? bm : bm - 8) * 64;
    const int n0 = bn * 64;

    __shared__ ushort_t As[64 * LDP];     // [m][k]
    __shared__ ushort_t Bs[64 * LDP];     // [n][k]

    const int tid = threadIdx.x;
    const int lane = tid & 63, w = tid >> 6;
    const int quad = lane >> 4, lrow = lane & 15;
    const int mw = (w & 1) * 32, nw = (w >> 1) * 32;

    const int ar = tid >> 2;              // 0..63
    const int ac = (tid & 3) * 8;         // 0,8,16,24

    floatx4 zero = {0.f, 0.f, 0.f, 0.f};
    floatx4 acc[2][2] = {{zero, zero}, {zero, zero}};

    float4 a0 = *(const float4*)(A + (size_t)(m0 + ar) * HD + ac);
    float4 a1 = *(const float4*)(A + (size_t)(m0 + ar) * HD + ac + 4);
    uint4  bld = *(const uint4*)&WT[(size_t)(n0 + ar) * HD + ac];

    for (int k0 = 0; k0 < HD; k0 += 32) {
        __syncthreads();
        uint4 ap;
        ap.x = (uint_t)f2bf(a0.x) | ((uint_t)f2bf(a0.y) << 16);
        ap.y = (uint_t)f2bf(a0.z) | ((uint_t)f2bf(a0.w) << 16);
        ap.z = (uint_t)f2bf(a1.x) | ((uint_t)f2bf(a1.y) << 16);
        ap.w = (uint_t)f2bf(a1.z) | ((uint_t)f2bf(a1.w) << 16);
        *(uint4*)&As[ar * LDP + ac] = ap;
        *(uint4*)&Bs[ar * LDP + ac] = bld;
        __syncthreads();
        if (k0 + 32 < HD) {
            a0  = *(const float4*)(A + (size_t)(m0 + ar) * HD + k0 + 32 + ac);
            a1  = *(const float4*)(A + (size_t)(m0 + ar) * HD + k0 + 32 + ac + 4);
            bld = *(const uint4*)&WT[(size_t)(n0 + ar) * HD + k0 + 32 + ac];
        }
        short8 af[2], bf[2];
        #pragma unroll
        for (int i = 0; i < 2; ++i)
            af[i] = *(const short8*)&As[(mw + i * 16 + lrow) * LDP + quad * 8];
        #pragma unroll
        for (int j = 0; j < 2; ++j)
            bf[j] = *(const short8*)&Bs[(nw + j * 16 + lrow) * LDP + quad * 8];
        #pragma unroll
        for (int i = 0; i < 2; ++i)
            #pragma unroll
            for (int j = 0; j < 2; ++j)
                acc[i][j] = __builtin_amdgcn_mfma_f32_16x16x32_bf16(af[i], bf[j], acc[i][j], 0, 0, 0);
    }

    if (isQ) {
        #pragma unroll
        for (int i = 0; i < 2; ++i)
            #pragma unroll
            for (int j = 0; j < 2; ++j)
                #pragma unroll
                for (int r = 0; r < 4; ++r) {
                    const int row = m0 + mw + i * 16 + quad * 4 + r;
                    const int col = n0 + nw + j * 16 + lrow;
                    pq[(size_t)row * HD + col] = acc[i][j][r];
                }
    } else {
        #pragma unroll
        for (int i = 0; i < 2; ++i)
            #pragma unroll
            for (int j = 0; j < 2; ++j) {
                const int gm = m0 + mw + i * 16 + quad * 4;   // enc-local row (4 consecutive)
                const int b = gm >> 9, s = gm & 511;
                const int col = n0 + nw + j * 16 + lrow;
                ushort4 o;
                o.x = f2bf(acc[i][j][0]);
                o.y = f2bf(acc[i][j][1]);
                o.z = f2bf(acc[i][j][2]);
                o.w = f2bf(acc[i][j][3]);
                *(ushort4*)&peT[((size_t)b * HD + col) * SS + s] = o;
            }
    }
}

// ---------------- Kernel 2: partial scores, grid (B*T, 4), 256 threads x 2 s ----------------
__global__ __launch_bounds__(256) void score_part_kernel(
    const float* __restrict__ pq, const ushort_t* __restrict__ peT,
    const float* __restrict__ v, const int* __restrict__ lens,
    _Float16* __restrict__ sp)
{
    const int bt = blockIdx.x;
    const int hq = blockIdx.y;
    const int b = bt >> 7;
    const int tid = threadIdx.x;
    const int h0 = hq * 128;

    __shared__ float s_a[128];            // 2*log2e * pq
    __shared__ float s_w[128];            // -2 * v
    __shared__ float s_sumv;
    if (tid < 128) {
        s_a[tid] = CEXP * pq[(size_t)bt * HD + h0 + tid];
        s_w[tid] = -2.f * v[h0 + tid];
    }
    if (tid < 64) {
        float sv = v[h0 + tid] + v[h0 + 64 + tid];
        #pragma unroll
        for (int off = 32; off; off >>= 1) sv += __shfl_xor(sv, off, 64);
        if (tid == 0) s_sumv = sv;
    }
    __syncthreads();
    const int len = lens[b];
    const int s0 = tid * 2;
    if (s0 >= len) return;

    const ushort_t* col = peT + ((size_t)b * HD + h0) * SS + s0;
    float acc0 = 0.f, acc1 = 0.f;
    for (int hh = 0; hh < 128; hh += 8) {
        uint_t p[8];
        #pragma unroll
        for (int j = 0; j < 8; ++j) p[j] = *(const uint_t*)(col + (size_t)(hh + j) * SS);
        #pragma unroll
        for (int j = 0; j < 8; ++j) {
            const float a = s_a[hh + j], w = s_w[hh + j];
            float pl = __uint_as_float(p[j] << 16);
            float ph = __uint_as_float(p[j] & 0xffff0000u);
            float t0 = __builtin_amdgcn_rcpf(exp2f(fmaf(CEXP, pl, a)) + 1.f);
            float t1 = __builtin_amdgcn_rcpf(exp2f(fmaf(CEXP, ph, a)) + 1.f);
            acc0 = fmaf(w, t0, acc0);
            acc1 = fmaf(w, t1, acc1);
        }
    }
    const float sumv = s_sumv;
    _Float16 f0 = (_Float16)(sumv + acc0);
    _Float16 f1 = (_Float16)(sumv + acc1);
    uint_t pk = (uint_t)*(ushort_t*)&f0 | ((uint_t)*(ushort_t*)&f1 << 16);
    *(uint_t*)(sp + ((size_t)hq * (BB * TT) + bt) * SS + s0) = pk;
}

// ---------------- Kernel 3: combine partials + masked softmax -> alpha (zeros past len) --------
__global__ __launch_bounds__(512) void combine_kernel(
    const _Float16* __restrict__ sp, const int* __restrict__ lens,
    float* __restrict__ alpha)
{
    const int bt = blockIdx.x;
    const int b = bt >> 7;
    const int tid = threadIdx.x;
    const int wave = tid >> 6;
    __shared__ float s_red[16];

    const int len = lens[b];
    float sc = -INFINITY;
    if (tid < len) {
        const size_t i = (size_t)bt * SS + tid;
        const size_t st = (size_t)BB * TT * SS;
        sc = (float)sp[i] + (float)sp[i + st] + (float)sp[i + 2 * st] + (float)sp[i + 3 * st];
    }
    float m = sc;
    #pragma unroll
    for (int off = 32; off; off >>= 1) m = fmaxf(m, __shfl_xor(m, off, 64));
    if ((tid & 63) == 0) s_red[wave] = m;
    __syncthreads();
    m = s_red[0];
    #pragma unroll
    for (int w2 = 1; w2 < 8; ++w2) m = fmaxf(m, s_red[w2]);

    float e = (tid < len) ? __expf(sc - m) : 0.f;
    float sum = e;
    #pragma unroll
    for (int off = 32; off; off >>= 1) sum += __shfl_xor(sum, off, 64);
    if ((tid & 63) == 0) s_red[8 + wave] = sum;
    __syncthreads();
    float total = s_red[8];
    #pragma unroll
    for (int w2 = 1; w2 < 8; ++w2) total += s_red[8 + w2];

    alpha[(size_t)bt * SS + tid] = e * __builtin_amdgcn_rcpf(total);
}

// ---------------- Kernel 4: ctx = alpha @ enc via MFMA, bf16 out into cq[:, 0:512] ------------
#define LDA_A 40
#define LDA_B 76
__global__ __launch_bounds__(256) void ctx_kernel(
    const float* __restrict__ alpha, const float* __restrict__ enc,
    const int* __restrict__ lens, ushort_t* __restrict__ cq)
{
    const int b = blockIdx.x;
    const int t0 = blockIdx.y * 16;
    const int h0 = blockIdx.z * 64;
    __shared__ ushort_t sA[16 * LDA_A];   // [t][s]
    __shared__ ushort_t sB[32 * LDA_B];   // [s][h]  (natural; frag reads strided)
    const int tid = threadIdx.x;
    const int lane = tid & 63, w = tid >> 6;
    const int quad = lane >> 4, lrow = lane & 15;
    const int nw = w * 16;
    const int len = lens[b];

    const int ar  = tid >> 4;          // 0..15  (t)
    const int ac2 = (tid & 15) * 2;    // 0..30  (s pair)
    const int br  = tid >> 3;          // 0..31  (s)
    const int bc8 = (tid & 7) * 8;     // h offset

    floatx4 acc = {0.f, 0.f, 0.f, 0.f};

    for (int s0 = 0; s0 < len; s0 += 32) {
        __syncthreads();
        {
            float2 a2 = *(const float2*)(alpha + (size_t)(b * TT + t0 + ar) * SS + s0 + ac2);
            uint_t pk = (uint_t)f2bf(a2.x) | ((uint_t)f2bf(a2.y) << 16);
            *(uint_t*)&sA[ar * LDA_A + ac2] = pk;
            const float* erow = enc + (size_t)(b * SS + s0 + br) * HD + h0 + bc8;
            float4 e0 = *(const float4*)erow;
            float4 e1 = *(const float4*)(erow + 4);
            uint2 w0, w1;
            w0.x = (uint_t)f2bf(e0.x) | ((uint_t)f2bf(e0.y) << 16);
            w0.y = (uint_t)f2bf(e0.z) | ((uint_t)f2bf(e0.w) << 16);
            w1.x = (uint_t)f2bf(e1.x) | ((uint_t)f2bf(e1.y) << 16);
            w1.y = (uint_t)f2bf(e1.z) | ((uint_t)f2bf(e1.w) << 16);
            *(uint2*)&sB[br * LDA_B + bc8] = w0;
            *(uint2*)&sB[br * LDA_B + bc8 + 4] = w1;
        }
        __syncthreads();
        short8 af = *(const short8*)&sA[lrow * LDA_A + quad * 8];
        short8 bf;
        #pragma unroll
        for (int j = 0; j < 8; ++j)
            bf[j] = (short)sB[(quad * 8 + j) * LDA_B + nw + lrow];
        acc = __builtin_amdgcn_mfma_f32_16x16x32_bf16(af, bf, acc, 0, 0, 0);
    }
    #pragma unroll
    for (int r = 0; r < 4; ++r)
        cq[(size_t)(b * TT + t0 + quad * 4 + r) * 1024 + h0 + nw + lrow] = f2bf(acc[r]);
}

// ---------------- Kernel 5: out = tanh(cq @ WTo^T), MFMA, 32x64 tiles ----------------
__global__ __launch_bounds__(256) void out_kernel(
    const ushort_t* __restrict__ cq, const ushort_t* __restrict__ WTo,
    float* __restrict__ out)
{
    const int m0 = blockIdx.x * 32;
    const int n0 = blockIdx.y * 64;

    __shared__ ushort_t As[32 * LDP];     // [m][k]
    __shared__ ushort_t Bs[64 * LDP];     // [n][k]

    const int tid = threadIdx.x;
    const int lane = tid & 63, w = tid >> 6;
    const int quad = lane >> 4, lrow = lane & 15;
    const int mw = (w & 1) * 16, nw = (w >> 1) * 32;

    const int ar = tid >> 3, ac4 = (tid & 7) * 4;   // A: uint2 (4 u16)
    const int br = tid >> 2, bc8 = (tid & 3) * 8;   // B: uint4 (8 u16)

    floatx4 zero = {0.f, 0.f, 0.f, 0.f};
    floatx4 acc[2] = {zero, zero};

    uint2 av = *(const uint2*)&cq[(size_t)(m0 + ar) * 1024 + ac4];
    uint4 bv = *(const uint4*)&WTo[(size_t)(n0 + br) * 1024 + bc8];

    for (int k0 = 0; k0 < 1024; k0 += 32) {
        __syncthreads();
        *(uint2*)&As[ar * LDP + ac4] = av;
        *(uint4*)&Bs[br * LDP + bc8] = bv;
        __syncthreads();
        if (k0 + 32 < 1024) {
            av = *(const uint2*)&cq[(size_t)(m0 + ar) * 1024 + k0 + 32 + ac4];
            bv = *(const uint4*)&WTo[(size_t)(n0 + br) * 1024 + k0 + 32 + bc8];
        }
        short8 af = *(const short8*)&As[(mw + lrow) * LDP + quad * 8];
        #pragma unroll
        for (int j = 0; j < 2; ++j) {
            short8 bf8 = *(const short8*)&Bs[(nw + j * 16 + lrow) * LDP + quad * 8];
            acc[j] = __builtin_amdgcn_mfma_f32_16x16x32_bf16(af, bf8, acc[j], 0, 0, 0);
        }
    }
    #pragma unroll
    for (int j = 0; j < 2; ++j)
        #pragma unroll
        for (int r = 0; r < 4; ++r) {
            const int row = m0 + mw + quad * 4 + r;
            const int col = n0 + nw + j * 16 + lrow;
            out[(size_t)row * HD + col] = tanh_e(acc[j][r]);
        }
}

extern "C" void kernel_launch(void* const* d_in, const int* in_sizes, int n_in,
                              void* d_out, int out_size, void* d_ws, size_t ws_size,
                              hipStream_t stream) {
    (void)in_sizes; (void)n_in; (void)out_size; (void)ws_size;
    const float* query = (const float*)d_in[0];   // (B,T,H)
    const float* enc   = (const float*)d_in[1];   // (B,S,H)
    const int*   lens  = (const int*)d_in[2];     // (B,)
    const float* W_h   = (const float*)d_in[3];   // (H,H)
    const float* W_s   = (const float*)d_in[4];   // (H,H)
    const float* v     = (const float*)d_in[5];   // (H,)
    const float* W_out = (const float*)d_in[6];   // (2H,H)
    float* out = (float*)d_out;

    // workspace layout (~9 MB, no aliasing needed)
    ushort_t* WTs   = (ushort_t*)d_ws;                          // 512 KB
    ushort_t* WTh   = WTs + (size_t)HD * HD;                    // 512 KB
    ushort_t* WTo   = WTh + (size_t)HD * HD;                    // 1 MB
    float*    pq    = (float*)(WTo + (size_t)HD * 2 * HD);      // 1 MB
    ushort_t* peT   = (ushort_t*)(pq + (size_t)BB * TT * HD);   // 2 MB (bf16)
    _Float16* sp    = (_Float16*)(peT + (size_t)BB * HD * SS);  // 2 MB (fp16 partials)
    float*    alpha = (float*)(sp + (size_t)4 * BB * TT * SS);  // 1 MB
    ushort_t* cq    = (ushort_t*)(alpha + (size_t)BB * TT * SS);// 1 MB ([ctx|q] bf16)

    wtrans_kernel<<<dim3(1152), 256, 0, stream>>>(W_s, W_h, W_out, query, WTs, WTh, WTo, cq);
    proj_kernel<<<dim3(40, 8), 256, 0, stream>>>(query, enc, WTs, WTh, pq, peT);
    score_part_kernel<<<dim3(BB * TT, 4), 256, 0, stream>>>(pq, peT, v, lens, sp);
    combine_kernel<<<dim3(BB * TT), 512, 0, stream>>>(sp, lens, alpha);
    ctx_kernel<<<dim3(BB, TT / 16, HD / 64), 256, 0, stream>>>(alpha, enc, lens, cq);
    out_kernel<<<dim3(16, 8), 256, 0, stream>>>(cq, WTo, out);
}